// Round 3
// baseline (150.156 us; speedup 1.0000x reference)
//
#include <hip/hip_runtime.h>
#include <hip/hip_bf16.h>

// EmbeddingDropout: out[b,s,:] = weight[x[b,s],:] * mask[x[b,s]]
// B*S = 16384 tokens, D = 512 (128 float4 per row).
// 32 threads per token; each thread handles 4 float4s (cols c, c+32, c+64, c+96)
// from the SAME row: 1 index load + 1 mask load + 4 independent weight loads
// -> 4x memory-level parallelism per thread, 4x fewer redundant scalar loads.
// Non-temporal stores (native ext_vector_type, since the builtin rejects
// HIP_vector_type): output is write-once streaming, keep L2/L3 for weight.

typedef float vfloat4 __attribute__((ext_vector_type(4)));

__global__ __launch_bounds__(256) void EmbeddingDropout_70592082477707_kernel(
    const int* __restrict__ x,          // [B*S] token ids (int32)
    const vfloat4* __restrict__ w,      // [V, 128] weight as float4
    const float* __restrict__ mask,     // [V] per-row dropout scale
    vfloat4* __restrict__ out)          // [B*S, 128]
{
    int t = blockIdx.x * blockDim.x + threadIdx.x;   // 524288 threads total
    int token = t >> 5;                               // 32 threads per token
    int c     = t & 31;                               // base col (float4 units)

    int row = x[token];
    float m = mask[row];

    const vfloat4* wr = w + (size_t)row * 128 + c;
    vfloat4 v0 = wr[0];
    vfloat4 v1 = wr[32];
    vfloat4 v2 = wr[64];
    vfloat4 v3 = wr[96];

    v0 *= m;
    v1 *= m;
    v2 *= m;
    v3 *= m;

    vfloat4* o = out + (size_t)token * 128 + c;
    __builtin_nontemporal_store(v0, o);
    __builtin_nontemporal_store(v1, o + 32);
    __builtin_nontemporal_store(v2, o + 64);
    __builtin_nontemporal_store(v3, o + 96);
}

extern "C" void kernel_launch(void* const* d_in, const int* in_sizes, int n_in,
                              void* d_out, int out_size, void* d_ws, size_t ws_size,
                              hipStream_t stream) {
    const int*     x    = (const int*)d_in[0];      // [B*S] int32
    const vfloat4* w    = (const vfloat4*)d_in[1];  // [V, 512] fp32 -> float4
    const float*   mask = (const float*)d_in[2];    // [V] fp32
    vfloat4*       out  = (vfloat4*)d_out;          // [B*S, 512] fp32 -> float4

    // 16384 tokens * 32 threads/token = 524288 threads = 2048 blocks of 256
    int n_threads = (out_size / 4) / 4;             // one thread per 4 float4
    int block = 256;
    int grid = (n_threads + block - 1) / block;     // 2048

    EmbeddingDropout_70592082477707_kernel<<<grid, block, 0, stream>>>(
        x, w, mask, out);
}